// Round 3
// baseline (9953.470 us; speedup 1.0000x reference)
//
#include <hip/hip_runtime.h>
#include <stdint.h>

// SNN membrane scan + spike + double-cumsum: StreamScan-style decoupled
// lookback. T split into NCH=16 chunks x 256 channel-blocks = 4096 blocks
// (~16 waves/CU) -> memory parallelism from TLP instead of 1-wave heroics.
// Exactness: each chunk re-runs the IDENTICAL sequential fmaf chain, seeded
// by the exact (m, c1, z) carry from the previous chunk via device-scope
// release/acquire flags -> bit-identical to the single-thread scan.
// Deadlock-free: virtual block id from atomicAdd in start order, so every
// dependency points to an already-started (resident or finished) block.

#define T_LEN 1024
#define N_IN  512
#define BN    16384          // BATCH * N_IN
#define NCH   16             // chunks along T
#define CT    (T_LEN / NCH)  // 64 timesteps per chunk
#define CB    (BN / 64)      // 256 channel-blocks (64 channels each)
#define G     8              // timesteps per prefetch group

// workspace layout (bytes)
#define WS_COUNTER 0
#define WS_FLAGS   4                         // (NCH-1)*CB flags
#define WS_ZERO_BYTES (4 + (NCH - 1) * CB * 4)
#define WS_PM      16384                     // (NCH-1)*BN floats
#define WS_PC      (WS_PM + (NCH - 1) * BN * 4)
#define WS_PZ      (WS_PC + (NCH - 1) * BN * 4)

__global__ __launch_bounds__(64, 4) void snn_scan(
        const float* __restrict__ cur, const float* __restrict__ beta,
        const float* __restrict__ vini, const float* __restrict__ vth,
        float* __restrict__ gz, float* __restrict__ zo, float* __restrict__ ml,
        uint32_t* counter, uint32_t* flags, float* pm, int* pc, int* pz)
{
    const int tid = threadIdx.x;
    uint32_t vid = 0;
    if (tid == 0)
        vid = __hip_atomic_fetch_add(counter, 1u, __ATOMIC_RELAXED,
                                     __HIP_MEMORY_SCOPE_AGENT);
    vid = __shfl(vid, 0);

    const int chunk = vid / CB;          // earlier-started blocks get earlier chunks
    const int cb    = vid % CB;
    const int ch    = cb * 64 + tid;     // channel = b*N + n
    const float bta = beta[ch & (N_IN - 1)];

    const size_t base = (size_t)chunk * CT * BN + ch;
    const float* cp = cur + base;
    const float* vp = vth + base;
    float* gp = gz + base;
    float* zp = zo + base;

    // Issue first two load groups BEFORE waiting on the carry (overlap).
    float cA[G], vA[G], cB_[G], vB_[G];
#pragma unroll
    for (int u = 0; u < G; ++u) { cA[u] = cp[(size_t)u * BN];       vA[u] = vp[(size_t)u * BN]; }
#pragma unroll
    for (int u = 0; u < G; ++u) { cB_[u] = cp[(size_t)(G + u) * BN]; vB_[u] = vp[(size_t)(G + u) * BN]; }

    float m; int c1, z;
    if (chunk == 0) {
        m = vini[ch]; c1 = 0; z = 0;
    } else {
        uint32_t* flagp = flags + (size_t)(chunk - 1) * CB + cb;
        while (__hip_atomic_load(flagp, __ATOMIC_ACQUIRE,
                                 __HIP_MEMORY_SCOPE_AGENT) == 0u)
            __builtin_amdgcn_s_sleep(16);   // ~1k cyc poll period: cap spin traffic
        const size_t slot = (size_t)(chunk - 1) * BN + ch;
        m  = __hip_atomic_load(pm + slot, __ATOMIC_RELAXED, __HIP_MEMORY_SCOPE_AGENT);
        c1 = __hip_atomic_load(pc + slot, __ATOMIC_RELAXED, __HIP_MEMORY_SCOPE_AGENT);
        z  = __hip_atomic_load(pz + slot, __ATOMIC_RELAXED, __HIP_MEMORY_SCOPE_AGENT);
    }

#pragma unroll
    for (int g = 0; g < CT / G; ++g) {
        float (&cc)[G] = (g & 1) ? cB_ : cA;
        float (&vv)[G] = (g & 1) ? vB_ : vA;
#pragma unroll
        for (int u = 0; u < G; ++u) {
            m = fmaf(bta, m, cc[u]);        // exact reference chain order
            c1 += (m >= vv[u]) ? 1 : 0;     // Heaviside(m - vth)
            z  += c1;                       // double cumsum, exact in int
            const size_t off = (size_t)(g * G + u) * BN;
            gp[off] = (z == 1) ? 1.0f : 0.0f;
            zp[off] = (float)z;
        }
        if (g + 2 < CT / G) {               // refill this buffer for group g+2
#pragma unroll
            for (int u = 0; u < G; ++u) {
                cc[u] = cp[(size_t)((g + 2) * G + u) * BN];
                vv[u] = vp[(size_t)((g + 2) * G + u) * BN];
            }
        }
    }

    if (chunk < NCH - 1) {
        const size_t slot = (size_t)chunk * BN + ch;
        __hip_atomic_store(pm + slot, m,  __ATOMIC_RELAXED, __HIP_MEMORY_SCOPE_AGENT);
        __hip_atomic_store(pc + slot, c1, __ATOMIC_RELAXED, __HIP_MEMORY_SCOPE_AGENT);
        __hip_atomic_store(pz + slot, z,  __ATOMIC_RELAXED, __HIP_MEMORY_SCOPE_AGENT);
        if (tid == 0)   // release: wave-level s_waitcnt drains all lanes' stores
            __hip_atomic_store(flags + (size_t)chunk * CB + cb, 1u,
                               __ATOMIC_RELEASE, __HIP_MEMORY_SCOPE_AGENT);
    } else {
        ml[ch] = m;     // m_last (B,N)
    }
}

extern "C" void kernel_launch(void* const* d_in, const int* in_sizes, int n_in,
                              void* d_out, int out_size, void* d_ws, size_t ws_size,
                              hipStream_t stream) {
    const float* cur  = (const float*)d_in[0];   // (T,B,N) fp32
    const float* beta = (const float*)d_in[1];   // (N,)
    const float* vini = (const float*)d_in[2];   // (B,N)
    const float* vth  = (const float*)d_in[3];   // (T,B,N)
    float* gz = (float*)d_out;                   // (T,B,N)
    float* zo = gz + (size_t)T_LEN * BN;         // (T,B,N)
    float* ml = zo + (size_t)T_LEN * BN;         // (B,N)

    uint8_t* ws = (uint8_t*)d_ws;
    uint32_t* counter = (uint32_t*)(ws + WS_COUNTER);
    uint32_t* flags   = (uint32_t*)(ws + WS_FLAGS);
    float*    pm      = (float*)(ws + WS_PM);
    int*      pc      = (int*)(ws + WS_PC);
    int*      pz      = (int*)(ws + WS_PZ);

    // d_ws is poisoned 0xAA before every launch: zero counter + flags.
    hipMemsetAsync(ws, 0, WS_ZERO_BYTES, stream);
    snn_scan<<<NCH * CB, 64, 0, stream>>>(cur, beta, vini, vth, gz, zo, ml,
                                          counter, flags, pm, pc, pz);
}

// Round 4
// 636.423 us; speedup vs baseline: 15.6397x; 15.6397x over previous
//
#include <hip/hip_runtime.h>
#include <stdint.h>

// SNN membrane scan + spike + double-cumsum: decoupled-lookback over T.
// T split into NCH=8 chunks x 256 channel-blocks = 2048 blocks (8 waves/CU).
// Exactness: each chunk replays the IDENTICAL sequential fmaf chain seeded by
// the exact (m, c1, z) carry of the previous chunk -> bit-identical (absmax 0).
// R3 lesson: NO cache-maintenance ops in the sync path. Poll with RELAXED
// agent-scope loads (LLC-direct, no buffer_inv); producer orders carries vs
// flag with a raw s_waitcnt vmcnt(0) (completion at the coherence point)
// instead of a release fence (no buffer_wbl2 L2-writeback storm).
// Deadlock-free: virtual block id from atomicAdd in start order.

#define T_LEN 1024
#define N_IN  512
#define BN    16384          // BATCH * N_IN
#define NCH   8              // chunks along T
#define CT    (T_LEN / NCH)  // 128 timesteps per chunk
#define CB    (BN / 64)      // 256 channel-blocks (64 channels each)
#define G     8              // timesteps per prefetch group

// workspace layout (bytes)
#define WS_COUNTER 0
#define WS_FLAGS   4                             // (NCH-1)*CB flags
#define WS_ZERO_BYTES (4 + (NCH - 1) * CB * 4)   // 7172
#define WS_PM      16384                         // (NCH-1)*BN floats
#define WS_PC      (WS_PM + (NCH - 1) * BN * 4)
#define WS_PZ      (WS_PC + (NCH - 1) * BN * 4)

__global__ __launch_bounds__(64, 4) void snn_scan(
        const float* __restrict__ cur, const float* __restrict__ beta,
        const float* __restrict__ vini, const float* __restrict__ vth,
        float* __restrict__ gz, float* __restrict__ zo, float* __restrict__ ml,
        uint32_t* counter, uint32_t* flags, float* pm, int* pc, int* pz)
{
    const int tid = threadIdx.x;
    uint32_t vid = 0;
    if (tid == 0)
        vid = __hip_atomic_fetch_add(counter, 1u, __ATOMIC_RELAXED,
                                     __HIP_MEMORY_SCOPE_AGENT);
    vid = __shfl(vid, 0);

    const int chunk = vid / CB;          // earlier-started blocks get earlier chunks
    const int cb    = vid % CB;
    const int ch    = cb * 64 + tid;     // channel = b*N + n
    const float bta = beta[ch & (N_IN - 1)];

    const size_t base = (size_t)chunk * CT * BN + ch;
    const float* cp = cur + base;
    const float* vp = vth + base;
    float* gp = gz + base;
    float* zp = zo + base;

    // Issue first two load groups BEFORE waiting on the carry (overlap).
    float cA[G], vA[G], cB_[G], vB_[G];
#pragma unroll
    for (int u = 0; u < G; ++u) { cA[u] = cp[(size_t)u * BN];        vA[u] = vp[(size_t)u * BN]; }
#pragma unroll
    for (int u = 0; u < G; ++u) { cB_[u] = cp[(size_t)(G + u) * BN]; vB_[u] = vp[(size_t)(G + u) * BN]; }

    float m; int c1, z;
    if (chunk == 0) {
        m = vini[ch]; c1 = 0; z = 0;
    } else {
        uint32_t* flagp = flags + (size_t)(chunk - 1) * CB + cb;
        // RELAXED poll: plain LLC read each iteration, zero cache-maintenance.
        while (__hip_atomic_load(flagp, __ATOMIC_RELAXED,
                                 __HIP_MEMORY_SCOPE_AGENT) == 0u)
            __builtin_amdgcn_s_sleep(4);         // ~256 cyc between polls
        asm volatile("" ::: "memory");           // no compiler hoist of carry loads
        const size_t slot = (size_t)(chunk - 1) * BN + ch;
        // Carries were complete at the LLC before flag became visible.
        m  = __hip_atomic_load(pm + slot, __ATOMIC_RELAXED, __HIP_MEMORY_SCOPE_AGENT);
        c1 = __hip_atomic_load(pc + slot, __ATOMIC_RELAXED, __HIP_MEMORY_SCOPE_AGENT);
        z  = __hip_atomic_load(pz + slot, __ATOMIC_RELAXED, __HIP_MEMORY_SCOPE_AGENT);
    }

#pragma unroll
    for (int g = 0; g < CT / G; ++g) {
        float (&cc)[G] = (g & 1) ? cB_ : cA;
        float (&vv)[G] = (g & 1) ? vB_ : vA;
#pragma unroll
        for (int u = 0; u < G; ++u) {
            m = fmaf(bta, m, cc[u]);        // exact reference chain order
            c1 += (m >= vv[u]) ? 1 : 0;     // Heaviside(m - vth)
            z  += c1;                       // double cumsum, exact in int
            const size_t off = (size_t)(g * G + u) * BN;
            gp[off] = (z == 1) ? 1.0f : 0.0f;
            zp[off] = (float)z;
        }
        if (g + 2 < CT / G) {               // refill this buffer for group g+2
#pragma unroll
            for (int u = 0; u < G; ++u) {
                cc[u] = cp[(size_t)((g + 2) * G + u) * BN];
                vv[u] = vp[(size_t)((g + 2) * G + u) * BN];
            }
        }
    }

    if (chunk < NCH - 1) {
        const size_t slot = (size_t)chunk * BN + ch;
        // Carry stores: agent-scope relaxed atomics -> complete at the LLC.
        __hip_atomic_store(pm + slot, m,  __ATOMIC_RELAXED, __HIP_MEMORY_SCOPE_AGENT);
        __hip_atomic_store(pc + slot, c1, __ATOMIC_RELAXED, __HIP_MEMORY_SCOPE_AGENT);
        __hip_atomic_store(pz + slot, z,  __ATOMIC_RELAXED, __HIP_MEMORY_SCOPE_AGENT);
        // Order carries-before-flag by COMPLETION, not by cache writeback:
        // single wave per block => vmcnt(0) covers all 64 lanes' stores.
        asm volatile("s_waitcnt vmcnt(0)" ::: "memory");
        if (tid == 0)
            __hip_atomic_store(flags + (size_t)chunk * CB + cb, 1u,
                               __ATOMIC_RELAXED, __HIP_MEMORY_SCOPE_AGENT);
    } else {
        ml[ch] = m;     // m_last (B,N)
    }
}

extern "C" void kernel_launch(void* const* d_in, const int* in_sizes, int n_in,
                              void* d_out, int out_size, void* d_ws, size_t ws_size,
                              hipStream_t stream) {
    const float* cur  = (const float*)d_in[0];   // (T,B,N) fp32
    const float* beta = (const float*)d_in[1];   // (N,)
    const float* vini = (const float*)d_in[2];   // (B,N)
    const float* vth  = (const float*)d_in[3];   // (T,B,N)
    float* gz = (float*)d_out;                   // (T,B,N)
    float* zo = gz + (size_t)T_LEN * BN;         // (T,B,N)
    float* ml = zo + (size_t)T_LEN * BN;         // (B,N)

    uint8_t* ws = (uint8_t*)d_ws;
    uint32_t* counter = (uint32_t*)(ws + WS_COUNTER);
    uint32_t* flags   = (uint32_t*)(ws + WS_FLAGS);
    float*    pm      = (float*)(ws + WS_PM);
    int*      pc      = (int*)(ws + WS_PC);
    int*      pz      = (int*)(ws + WS_PZ);

    // d_ws is poisoned 0xAA before every launch: zero counter + flags.
    hipMemsetAsync(ws, 0, WS_ZERO_BYTES, stream);
    snn_scan<<<NCH * CB, 64, 0, stream>>>(cur, beta, vini, vth, gz, zo, ml,
                                          counter, flags, pm, pc, pz);
}

// Round 5
// 261.183 us; speedup vs baseline: 38.1092x; 2.4367x over previous
//
#include <hip/hip_runtime.h>
#include <stdint.h>

// SNN membrane scan + spike + double-cumsum: decoupled lookback over T with
// SEED-INDEPENDENT LDS pre-staging. T split into NCH=8 chunks x 256
// channel-blocks. Each block eagerly DMAs its whole 64 KB chunk into LDS via
// global_load_lds (zero VGPR cost -> compiler cannot collapse it; R4 lesson)
// BEFORE waiting on the carry. Post-seed critical path per link is only
// flag-detect + carry-read + 128-step compute from LDS (~4 us), while later
// chunks' staging overlaps (2 blocks/CU resident = frontier + next).
// Exactness: identical sequential fmaf chain seeded by the exact packed
// (m,c1,z) carry -> bit-identical (absmax 0 in R2-R4).
// Sync: atomic-RMW reads (always at coherence point; immune to stale L2
// across graph replays), relaxed agent stores + raw vmcnt(0) ordering; no
// cache-maintenance instructions anywhere (R3 livelock lesson).
// Deadlock-free: vid from atomicAdd in start order -> resident set always
// contains every block of the lowest unfinished chunk.

#define T_LEN 1024
#define N_IN  512
#define BN    16384          // BATCH * N_IN
#define NCH   8              // chunks along T
#define CT    (T_LEN / NCH)  // 128 timesteps per chunk
#define CB    (BN / 64)      // 256 channel-blocks (64 channels each)

// workspace layout (bytes)
#define WS_COUNTER 0
#define WS_FLAGS   4                             // (NCH-1)*CB u32 flags
#define WS_ZERO_BYTES (4 + (NCH - 1) * CB * 4)   // 7172
#define WS_CARRY   16384                         // (NCH-1)*BN u64 packed carries

#define AS_GLOBAL(p) (const __attribute__((address_space(1))) void*)(p)
#define AS_LDS(p)    (__attribute__((address_space(3))) void*)(p)

__global__ __launch_bounds__(64, 1) void snn_scan(
        const float* __restrict__ cur, const float* __restrict__ beta,
        const float* __restrict__ vini, const float* __restrict__ vth,
        float* __restrict__ gz, float* __restrict__ zo, float* __restrict__ ml,
        uint32_t* counter, uint32_t* flags, unsigned long long* carry)
{
    // 64 KB: whole chunk staged here. 160 KB/CU -> 2 blocks/CU resident.
    __shared__ float lc[CT][64];
    __shared__ float lv[CT][64];

    const int tid = threadIdx.x;
    uint32_t vid = 0;
    if (tid == 0)
        vid = __hip_atomic_fetch_add(counter, 1u, __ATOMIC_RELAXED,
                                     __HIP_MEMORY_SCOPE_AGENT);
    vid = __shfl(vid, 0);

    const int chunk = vid / CB;          // start order => oldest chunks first
    const int cb    = vid % CB;
    const int ch    = cb * 64 + tid;     // channel = b*N + n
    const float bta = beta[ch & (N_IN - 1)];

    const size_t base = (size_t)chunk * CT * BN + ch;
    const float* cp = cur + base;        // per-lane, lane-contiguous
    const float* vp = vth + base;
    float* gp = gz + base;
    float* zp = zo + base;

    // ---- Seed-independent staging: entire chunk HBM -> LDS, issued eagerly.
    // 256 x 256B DMA instrs; vmcnt caps at 63 outstanding (16 KB in flight).
#pragma unroll 4
    for (int t = 0; t < CT; ++t) {
        __builtin_amdgcn_global_load_lds(AS_GLOBAL(cp + (size_t)t * BN),
                                         AS_LDS(&lc[t][0]), 4, 0, 0);
        __builtin_amdgcn_global_load_lds(AS_GLOBAL(vp + (size_t)t * BN),
                                         AS_LDS(&lv[t][0]), 4, 0, 0);
    }

    // ---- Acquire exact seed.
    float m; int c1, z;
    if (chunk == 0) {
        m = vini[ch]; c1 = 0; z = 0;
    } else {
        uint32_t* flagp = flags + (size_t)(chunk - 1) * CB + cb;
        uint32_t f;
        do {                                  // lane-0 RMW poll (coherence point)
            f = 0;
            if (tid == 0)
                f = __hip_atomic_fetch_add(flagp, 0u, __ATOMIC_RELAXED,
                                           __HIP_MEMORY_SCOPE_AGENT);
            f = __shfl(f, 0);
            if (f == 0) __builtin_amdgcn_s_sleep(8);   // ~0.2 us between polls
        } while (f == 0);
        const unsigned long long pk = __hip_atomic_fetch_add(
            carry + (size_t)(chunk - 1) * BN + ch, 0ull,
            __ATOMIC_RELAXED, __HIP_MEMORY_SCOPE_AGENT);
        m  = __uint_as_float((uint32_t)(pk >> 32));
        c1 = (int)((pk >> 20) & 0x7FFu);      // c1 <= 1024: 11 bits
        z  = (int)(pk & 0xFFFFFu);            // z < 2^20 (max 524800)
    }
    // In-order vmcnt retirement: poll RMW already drained staging; explicit
    // for chunk 0 and as a compiler fence before LDS reads.
    asm volatile("s_waitcnt vmcnt(0)" ::: "memory");

    // ---- Exact sequential chain from LDS (~10 cyc/step).
#pragma unroll 8
    for (int t = 0; t < CT; ++t) {
        const float c = lc[t][tid];           // 2-way bank alias: free
        const float v = lv[t][tid];
        m = fmaf(bta, m, c);                  // exact reference chain order
        c1 += (m >= v) ? 1 : 0;               // Heaviside(m - vth)
        z  += c1;                             // double cumsum, exact in int
        const size_t off = (size_t)t * BN;
        gp[off] = (z == 1) ? 1.0f : 0.0f;     // gz = (z==1) ? 1 : 0
        zp[off] = (float)z;
    }

    // ---- Publish exact carry (packed u64), then flag; order by completion.
    if (chunk < NCH - 1) {
        const unsigned long long pk =
            ((unsigned long long)__float_as_uint(m) << 32) |
            ((unsigned long long)(uint32_t)c1 << 20) | (uint32_t)(uint32_t)z;
        __hip_atomic_store(carry + (size_t)chunk * BN + ch, pk,
                           __ATOMIC_RELAXED, __HIP_MEMORY_SCOPE_AGENT);
        asm volatile("s_waitcnt vmcnt(0)" ::: "memory");  // all lanes' stores done
        if (tid == 0)
            __hip_atomic_store(flags + (size_t)chunk * CB + cb, 1u,
                               __ATOMIC_RELAXED, __HIP_MEMORY_SCOPE_AGENT);
    } else {
        ml[ch] = m;                           // m_last (B,N)
    }
}

extern "C" void kernel_launch(void* const* d_in, const int* in_sizes, int n_in,
                              void* d_out, int out_size, void* d_ws, size_t ws_size,
                              hipStream_t stream) {
    const float* cur  = (const float*)d_in[0];   // (T,B,N) fp32
    const float* beta = (const float*)d_in[1];   // (N,)
    const float* vini = (const float*)d_in[2];   // (B,N)
    const float* vth  = (const float*)d_in[3];   // (T,B,N)
    float* gz = (float*)d_out;                   // (T,B,N)
    float* zo = gz + (size_t)T_LEN * BN;         // (T,B,N)
    float* ml = zo + (size_t)T_LEN * BN;         // (B,N)

    uint8_t* ws = (uint8_t*)d_ws;
    uint32_t* counter = (uint32_t*)(ws + WS_COUNTER);
    uint32_t* flags   = (uint32_t*)(ws + WS_FLAGS);
    unsigned long long* carry = (unsigned long long*)(ws + WS_CARRY);

    // d_ws is poisoned 0xAA before every launch: zero counter + flags.
    hipMemsetAsync(ws, 0, WS_ZERO_BYTES, stream);
    snn_scan<<<NCH * CB, 64, 0, stream>>>(cur, beta, vini, vth, gz, zo, ml,
                                          counter, flags, carry);
}

// Round 6
// 250.291 us; speedup vs baseline: 39.7675x; 1.0435x over previous
//
#include <hip/hip_runtime.h>
#include <stdint.h>

// SNN membrane scan + spike + double-cumsum: single-kernel warp-specialized
// producer/consumer. 256 persistent blocks (1/CU) x 4 waves. Wave 0 runs the
// exact sequential fmaf chain for its 64 channels over ALL T=1024 steps,
// reading from an LDS ring; waves 1-3 DMA segments (16 timesteps, 8 KB) into
// the ring with global_load_lds (zero VGPR cost -> allocator cannot collapse
// the pipeline, R4 lesson). All sync is intra-block LDS flags (no global
// atomics, no cache-maintenance ops -- R3 lesson; no inter-block phases --
// R5 lesson: 2-resident-chunk pipelining re-serialized into R1's 95 us).
// Exactness: bit-identical chain order -> absmax 0 as in R1-R5.
//
// Deadlock-free handshake: producer issues seg s only when progress >= s-6
// (slot s%7 free); ready[x] is flagged at issue of x+3 (vmcnt(31): in-order
// retirement => seg x+3 issued implies seg <= x+2 landed... flag lags issue
// by one own-segment = 3 global segments < ring depth 7).

#define T_LEN 1024
#define N_IN  512
#define BN    16384            // BATCH * N_IN
#define SEG   16               // timesteps per segment
#define NSEG  (T_LEN / SEG)    // 64 segments
#define NSLOT 7                // ring slots -> 56 KB (stay under 64 KB static LDS)
#define SLOT_B (SEG * 512)     // per t: c-row 256 B + v-row 256 B

#define AS_GLOBAL(p) (const __attribute__((address_space(1))) void*)(p)
#define AS_LDS(p)    (__attribute__((address_space(3))) void*)(p)

__global__ __launch_bounds__(256, 1) void snn_scan(
        const float* __restrict__ cur, const float* __restrict__ beta,
        const float* __restrict__ vini, const float* __restrict__ vth,
        float* __restrict__ gz, float* __restrict__ zo, float* __restrict__ ml)
{
    __shared__ __align__(16) char ring[NSLOT * SLOT_B];   // 57344 B
    __shared__ int ready[NSEG];
    __shared__ int progress;

    const int tid    = threadIdx.x;
    const int w      = tid >> 6;         // wave 0 = consumer, 1..3 = producers
    const int lane   = tid & 63;
    const int chbase = blockIdx.x * 64;  // this block's 64-channel group

    if (tid < NSEG) ready[tid] = 0;
    if (tid == NSEG) progress = 0;
    __syncthreads();                     // only barrier in the kernel

    if (w == 0) {
        // ---------------- consumer: exact sequential chain from the ring ----
        const int ch  = chbase + lane;   // channel = b*N + n
        const float bta = beta[ch & (N_IN - 1)];
        float m = vini[ch];
        int c1 = 0, z = 0;
        float* gp = gz + ch;
        float* zp = zo + ch;

        for (int seg = 0; seg < NSEG; ++seg) {
            while (__hip_atomic_load(&ready[seg], __ATOMIC_RELAXED,
                                     __HIP_MEMORY_SCOPE_WORKGROUP) == 0)
                __builtin_amdgcn_s_sleep(1);
            asm volatile("" ::: "memory");
            const char* sb = ring + (seg % NSLOT) * SLOT_B + lane * 4;
#pragma unroll
            for (int t = 0; t < SEG; ++t) {
                const float c = *(const float*)(sb + t * 512);        // c-row
                const float v = *(const float*)(sb + t * 512 + 256);  // v-row
                m = fmaf(bta, m, c);             // exact reference chain order
                c1 += (m >= v) ? 1 : 0;          // Heaviside(m - vth)
                z  += c1;                        // double cumsum, exact in int
                const size_t off = (size_t)(seg * SEG + t) * BN;
                gp[off] = (z == 1) ? 1.0f : 0.0f;
                zp[off] = (float)z;
            }
            if (lane == 0)                       // free the slot
                __hip_atomic_store(&progress, seg + 1, __ATOMIC_RELAXED,
                                   __HIP_MEMORY_SCOPE_WORKGROUP);
        }
        ml[ch] = m;                              // m_last (B,N)
    } else {
        // ---------------- producers: DMA segments into the ring -------------
        const float* cp = cur + chbase + lane;   // per-lane global base
        const float* vp = vth + chbase + lane;
        int prev = -1;
        for (int s = w - 1; s < NSEG; s += 3) {  // round-robin ownership
            // ring space: previous occupant of slot s%7 is seg s-7
            while (__hip_atomic_load(&progress, __ATOMIC_RELAXED,
                                     __HIP_MEMORY_SCOPE_WORKGROUP) < s - (NSLOT - 1))
                __builtin_amdgcn_s_sleep(2);
            char* slot = ring + (s % NSLOT) * SLOT_B;
#pragma unroll
            for (int t = 0; t < SEG; ++t) {
                const size_t go = (size_t)(s * SEG + t) * BN;
                __builtin_amdgcn_global_load_lds(AS_GLOBAL(cp + go),
                                                 AS_LDS(slot + t * 512), 4, 0, 0);
                __builtin_amdgcn_global_load_lds(AS_GLOBAL(vp + go),
                                                 AS_LDS(slot + t * 512 + 256), 4, 0, 0);
            }
            if (prev >= 0) {
                // <=31 outstanding => oldest load of this seg retired =>
                // ALL loads of seg `prev` landed in LDS (in-order retirement).
                asm volatile("s_waitcnt vmcnt(31)" ::: "memory");
                if (lane == 0)
                    __hip_atomic_store(&ready[prev], 1, __ATOMIC_RELAXED,
                                       __HIP_MEMORY_SCOPE_WORKGROUP);
            }
            prev = s;
        }
        asm volatile("s_waitcnt vmcnt(0)" ::: "memory");
        if (lane == 0 && prev >= 0)
            __hip_atomic_store(&ready[prev], 1, __ATOMIC_RELAXED,
                               __HIP_MEMORY_SCOPE_WORKGROUP);
    }
}

extern "C" void kernel_launch(void* const* d_in, const int* in_sizes, int n_in,
                              void* d_out, int out_size, void* d_ws, size_t ws_size,
                              hipStream_t stream) {
    const float* cur  = (const float*)d_in[0];   // (T,B,N) fp32
    const float* beta = (const float*)d_in[1];   // (N,)
    const float* vini = (const float*)d_in[2];   // (B,N)
    const float* vth  = (const float*)d_in[3];   // (T,B,N)
    float* gz = (float*)d_out;                   // (T,B,N)
    float* zo = gz + (size_t)T_LEN * BN;         // (T,B,N)
    float* ml = zo + (size_t)T_LEN * BN;         // (B,N)
    // No workspace, no memset, no inter-block sync: one self-contained kernel.
    snn_scan<<<BN / 64, 256, 0, stream>>>(cur, beta, vini, vth, gz, zo, ml);
}